// Round 3
// baseline (96.212 us; speedup 1.0000x reference)
//
#include <hip/hip_runtime.h>
#include <math.h>

// st_VQEmbedding: z [B=16,N=4096,D=64] f32, emb [K=512,D=64] f32
// out = emb[argmin_k (x2 - 2*x.e_k) + e2_k], straight-through (q+x)-x.
// Bit-exact vs round-1/2 passing kernels: same FMA chains, same scan order,
// same tie-break (strict <, ascending k).
//
// R3 design: lane = point, wave = K-quarter. The e-row index is wave-uniform
// (readfirstlane-proven), so e loads go down the SCALAR pipe (s_load -> SGPR)
// and the VALU issues nothing but v_fmac_f32 vdst, s, v. This removes the LDS
// ds_read_b128 stream that bounded R2 at ~82us (12cyc x 2048/wave on the LDS pipe).

constexpr int K     = 512;
constexpr int NPTS  = 16 * 4096;   // 65536 points
constexpr int BLOCK = 256;
constexpr int NW    = 4;           // waves per block
constexpr int PPB   = 64;          // points per block (one per lane)
constexpr int KQ    = K / NW;      // 128 codes per wave

__global__ __launch_bounds__(BLOCK, 4)
void vq_st_kernel(const float* __restrict__ z,
                  const float* __restrict__ emb,
                  float* __restrict__ out)
{
    __shared__ float e2s[K];
    __shared__ float bestw[NW][PPB];
    __shared__ int   bidxw[NW][PPB];
    __shared__ int   bfin[PPB];

    const int tid  = threadIdx.x;
    const int lane = tid & 63;
    // wave id, forced wave-uniform so the k index is scalar-provable -> s_load
    const int w    = __builtin_amdgcn_readfirstlane(tid >> 6);

    const float4* ef4 = reinterpret_cast<const float4*>(emb);
    const float4* zf4 = reinterpret_cast<const float4*>(z);
    float4*       of4 = reinterpret_cast<float4*>(out);

    const int base = blockIdx.x * PPB;

    // ---- e2[k] = sum_d fl(e_kd^2), sequential, unfused (matches jnp) ----
    {
        #pragma clang fp contract(off)
        #pragma unroll
        for (int kk = 0; kk < K / BLOCK; ++kk) {
            const int k = tid + kk * BLOCK;
            const float4* row = ef4 + k * 16;
            float s = 0.0f;
            #pragma unroll
            for (int i = 0; i < 16; ++i) {
                float4 v = row[i];
                s = s + v.x * v.x;
                s = s + v.y * v.y;
                s = s + v.z * v.z;
                s = s + v.w * v.w;
            }
            e2s[k] = s;
        }
    }

    // ---- x row for this lane's point, kept in VGPRs ----
    const int pt = base + lane;
    float4 xv[16];
    #pragma unroll
    for (int i = 0; i < 16; ++i) xv[i] = zf4[pt * 16 + i];

    float x2 = 0.0f;
    {
        #pragma clang fp contract(off)
        #pragma unroll
        for (int i = 0; i < 16; ++i) {
            x2 = x2 + xv[i].x * xv[i].x;
            x2 = x2 + xv[i].y * xv[i].y;
            x2 = x2 + xv[i].z * xv[i].z;
            x2 = x2 + xv[i].w * xv[i].w;
        }
    }

    __syncthreads();   // e2s ready

    // ---- scan this wave's K-quarter; e rows via scalar loads ----
    const int k0 = w * KQ;
    float best = INFINITY;
    int   bi   = 0;

    for (int kk = 0; kk < KQ; kk += 2) {
        const int ka = k0 + kk;
        const int kb = ka + 1;
        const float4* ra = ef4 + ka * 16;   // wave-uniform -> s_load
        const float4* rb = ef4 + kb * 16;
        float a0 = 0.0f, a1 = 0.0f;         // two independent chains (ILP)
        #pragma unroll
        for (int j = 0; j < 16; ++j) {
            const float4 ea = ra[j];
            const float4 eb = rb[j];
            a0 = __builtin_fmaf(xv[j].x, ea.x, a0);
            a0 = __builtin_fmaf(xv[j].y, ea.y, a0);
            a0 = __builtin_fmaf(xv[j].z, ea.z, a0);
            a0 = __builtin_fmaf(xv[j].w, ea.w, a0);
            a1 = __builtin_fmaf(xv[j].x, eb.x, a1);
            a1 = __builtin_fmaf(xv[j].y, eb.y, a1);
            a1 = __builtin_fmaf(xv[j].z, eb.z, a1);
            a1 = __builtin_fmaf(xv[j].w, eb.w, a1);
        }
        // dist = (x2 - 2*dot) + e2 ; e2s[k] is a whole-wave broadcast read
        const float d0 = (x2 - 2.0f * a0) + e2s[ka];
        const float d1 = (x2 - 2.0f * a1) + e2s[kb];
        if (d0 < best) { best = d0; bi = ka; }   // strict <, ascending k
        if (d1 < best) { best = d1; bi = kb; }
    }

    bestw[w][lane] = best;
    bidxw[w][lane] = bi;
    __syncthreads();

    // ---- combine the 4 wave-quarters: ascending wave = ascending k ----
    if (tid < PPB) {
        float b  = bestw[0][tid];
        int   i0 = bidxw[0][tid];
        #pragma unroll
        for (int ww = 1; ww < NW; ++ww) {
            const float ob = bestw[ww][tid];
            const int   oi = bidxw[ww][tid];
            if (ob < b) { b = ob; i0 = oi; }   // strict < keeps lowest k-range
        }
        bfin[tid] = i0;
    }
    __syncthreads();

    // ---- dense epilogue: lane-linear float4 stores ----
    #pragma unroll
    for (int i = 0; i < (PPB * 16) / BLOCK; ++i) {   // 4 iters
        const int idx = i * BLOCK + tid;
        const int p   = idx >> 4;
        const int j   = idx & 15;
        const float4 q = ef4[bfin[p] * 16 + j];
        const float4 x = zf4[(base + p) * 16 + j];
        float4 o;
        o.x = (q.x + x.x) - x.x;
        o.y = (q.y + x.y) - x.y;
        o.z = (q.z + x.z) - x.z;
        o.w = (q.w + x.w) - x.w;
        of4[(base + p) * 16 + j] = o;
    }
}

extern "C" void kernel_launch(void* const* d_in, const int* in_sizes, int n_in,
                              void* d_out, int out_size, void* d_ws, size_t ws_size,
                              hipStream_t stream) {
    const float* z   = (const float*)d_in[0];
    const float* emb = (const float*)d_in[1];
    float* out = (float*)d_out;

    const int grid = NPTS / PPB;   // 1024 blocks -> 4 per CU, 16 waves/CU
    vq_st_kernel<<<grid, BLOCK, 0, stream>>>(z, emb, out);
}